// Round 1
// baseline (9661.980 us; speedup 1.0000x reference)
//
#include <hip/hip_runtime.h>
#include <hip/hip_bf16.h>
#include <stdint.h>

#define NN   50000
#define EE   800000
#define RR   8
#define CIN  512
#define CHID 256
#define COUT 512

typedef __bf16 bf16x8 __attribute__((ext_vector_type(8)));
typedef __bf16 bf16x4 __attribute__((ext_vector_type(4)));
typedef float  f32x4  __attribute__((ext_vector_type(4)));

static_assert(CIN % 64 == 0 && CHID % 128 == 0 && COUT % 128 == 0, "tile divisibility");

__device__ __forceinline__ f32x4 mfma_bf16(bf16x8 a, bf16x8 b, f32x4 c) {
    return __builtin_amdgcn_mfma_f32_16x16x32_bf16(a, b, c, 0, 0, 0);
}

__device__ __forceinline__ void gload_lds16(const void* g, void* l) {
    __builtin_amdgcn_global_load_lds((const __attribute__((address_space(1))) void*)g,
                                     (__attribute__((address_space(3))) void*)l, 16, 0, 0);
}

// ---------------- prep: split fp32 -> (hi, lo) bf16 ----------------
__global__ void cvt_split(const float* __restrict__ in, __bf16* __restrict__ hi,
                          __bf16* __restrict__ lo, int n4) {
    int i = blockIdx.x * blockDim.x + threadIdx.x;
    if (i >= n4) return;
    f32x4 v = ((const f32x4*)in)[i];
    bf16x4 h, l;
#pragma unroll
    for (int j = 0; j < 4; ++j) {
        __bf16 hj = (__bf16)v[j];
        h[j] = hj;
        l[j] = (__bf16)(v[j] - (float)hj);
    }
    ((bf16x4*)hi)[i] = h;
    ((bf16x4*)lo)[i] = l;
}

// transpose + split: W[r][K][NC] -> Wt[r][NC][K] (hi, lo)
template <int NC>
__global__ void wprep(const float* __restrict__ W, __bf16* __restrict__ hi,
                      __bf16* __restrict__ lo, int K) {
    int r = blockIdx.z;
    int idx = blockIdx.x * blockDim.x + threadIdx.x;
    if (idx >= K * NC) return;
    int k = idx / NC, nc = idx % NC;
    float v = W[(size_t)r * K * NC + idx];
    __bf16 h = (__bf16)v;
    size_t o = (size_t)r * NC * K + (size_t)nc * K + k;
    hi[o] = h;
    lo[o] = (__bf16)(v - (float)h);
}

// ---------------- per-(rel,dst) edge counts ----------------
__global__ void count_edges(const int* __restrict__ et, const int* __restrict__ dst,
                            int* __restrict__ cnt) {
    int e = blockIdx.x * blockDim.x + threadIdx.x;
    if (e < EE) atomicAdd(&cnt[et[e] * NN + dst[e]], 1);
}

// ---------------- split-bf16 MFMA GEMM, 128x128 tile, BK=64 ----------------
// C[M,NC] = (Ah+Al)[M,K] @ (Bh+Bl)^T[NC,K]^T   (3-term split product)
// EPI 0: store fp32 C
// EPI 1: v += Cin + bias; relu; store (hi,lo) bf16 to Oh/Ol   (layer-1 finish -> h)
// EPI 2: v += Cin + bias; store fp32 C                        (layer-2 finish)
template <int K, int NC, int EPI>
__global__ __launch_bounds__(256, 2) void gemm_split(
    const __bf16* __restrict__ Ah, const __bf16* __restrict__ Al,
    const __bf16* __restrict__ Bh, const __bf16* __restrict__ Bl,
    float* __restrict__ C, const float* __restrict__ Cin,
    const float* __restrict__ bias,
    __bf16* __restrict__ Oh, __bf16* __restrict__ Ol, int M) {
    __shared__ __bf16 lds[32768];          // 64 KB: Ah|Al|Bh|Bl, each [128][64]
    __bf16* sAh = lds;
    __bf16* sAl = lds + 8192;
    __bf16* sBh = lds + 16384;
    __bf16* sBl = lds + 24576;

    const int tid  = threadIdx.x;
    const int lane = tid & 63;
    const int wid  = tid >> 6;
    const int wm   = wid >> 1, wn = wid & 1;
    const int row0 = blockIdx.x * 128;
    const int col0 = blockIdx.y * 128;

    f32x4 acc[4][4] = {};

    for (int ks = 0; ks < K / 64; ++ks) {
        const int k0 = ks * 64;
#pragma unroll
        for (int i = 0; i < 4; ++i) {
            int flat = i * 256 + tid;          // 1024 chunks of 8 bf16
            int rr = flat >> 3;
            int kc = (flat & 7) * 8;
            int ra = row0 + rr;
            ra = ra < M ? ra : M - 1;          // clamp tail rows (masked at store)
            size_t ga = (size_t)ra * K + k0 + kc;
            size_t gb = (size_t)(col0 + rr) * K + k0 + kc;
            gload_lds16(Ah + ga, sAh + flat * 8);
            gload_lds16(Al + ga, sAl + flat * 8);
            gload_lds16(Bh + gb, sBh + flat * 8);
            gload_lds16(Bl + gb, sBl + flat * 8);
        }
        __syncthreads();
#pragma unroll
        for (int kk = 0; kk < 2; ++kk) {
            const int ko = kk * 32 + (lane >> 4) * 8;
            bf16x8 fah[4], fal[4], fbh[4], fbl[4];
#pragma unroll
            for (int m = 0; m < 4; ++m) {
                int ar = wm * 64 + m * 16 + (lane & 15);
                fah[m] = *(const bf16x8*)(sAh + ar * 64 + ko);
                fal[m] = *(const bf16x8*)(sAl + ar * 64 + ko);
            }
#pragma unroll
            for (int n = 0; n < 4; ++n) {
                int br = wn * 64 + n * 16 + (lane & 15);
                fbh[n] = *(const bf16x8*)(sBh + br * 64 + ko);
                fbl[n] = *(const bf16x8*)(sBl + br * 64 + ko);
            }
#pragma unroll
            for (int m = 0; m < 4; ++m)
#pragma unroll
                for (int n = 0; n < 4; ++n) {
                    acc[m][n] = mfma_bf16(fah[m], fbh[n], acc[m][n]);
                    acc[m][n] = mfma_bf16(fal[m], fbh[n], acc[m][n]);
                    acc[m][n] = mfma_bf16(fah[m], fbl[n], acc[m][n]);
                }
        }
        __syncthreads();
    }

#pragma unroll
    for (int m = 0; m < 4; ++m)
#pragma unroll
        for (int n = 0; n < 4; ++n)
#pragma unroll
            for (int q = 0; q < 4; ++q) {
                int row = row0 + wm * 64 + m * 16 + (lane >> 4) * 4 + q;
                int col = col0 + wn * 64 + n * 16 + (lane & 15);
                if (row < M) {
                    size_t o = (size_t)row * NC + col;
                    float v = acc[m][n][q];
                    if (EPI >= 1) v += Cin[o] + bias[col];
                    if (EPI == 1) {
                        v = fmaxf(v, 0.0f);
                        __bf16 h = (__bf16)v;
                        Oh[o] = h;
                        Ol[o] = (__bf16)(v - (float)h);
                    } else {
                        C[o] = v;
                    }
                }
            }
}

// ---------------- edge scatter: acc[dst] += xW[src] / cnt[rel,dst] ----------------
// one wave handles one edge chunk; lanes cover the feature row contiguously (float4)
template <int NC>
__global__ void scatter_edges(const float* __restrict__ xW, const int* __restrict__ src,
                              const int* __restrict__ dst, const int* __restrict__ et,
                              const int* __restrict__ cnt, float* __restrict__ acc, int rel) {
    constexpr int SH = (NC == 256) ? 6 : 7;   // threads per edge = NC/4
    const int total = EE << SH;
    const int step = gridDim.x * blockDim.x;
    for (int t = blockIdx.x * blockDim.x + threadIdx.x; t < total; t += step) {
        const int e = t >> SH;
        if (et[e] != rel) continue;           // wave-uniform (all lanes same edge)
        const int c = t & ((1 << SH) - 1);
        const int s = src[e], d = dst[e];
        const float inv = 1.0f / (float)cnt[rel * NN + d];
        f32x4 v = ((const f32x4*)(xW + (size_t)s * NC))[c];
        float* p = acc + (size_t)d * NC + c * 4;
        atomicAdd(p + 0, v[0] * inv);         // device-scope: XCD-safe
        atomicAdd(p + 1, v[1] * inv);
        atomicAdd(p + 2, v[2] * inv);
        atomicAdd(p + 3, v[3] * inv);
    }
}

// ---------------- row-wise L2 normalize (one wave per 512-col row) ----------------
__global__ void l2norm(float* __restrict__ out) {
    int row = blockIdx.x * 4 + (threadIdx.x >> 6);
    int lane = threadIdx.x & 63;
    if (row >= NN) return;
    float* p = out + (size_t)row * COUT;
    f32x4 a = ((const f32x4*)p)[lane];
    f32x4 b = ((const f32x4*)p)[lane + 64];
    float ss = a[0] * a[0] + a[1] * a[1] + a[2] * a[2] + a[3] * a[3] +
               b[0] * b[0] + b[1] * b[1] + b[2] * b[2] + b[3] * b[3];
#pragma unroll
    for (int m = 32; m >= 1; m >>= 1) ss += __shfl_xor(ss, m, 64);
    const float s = 1.0f / fmaxf(sqrtf(ss), 1e-12f);
#pragma unroll
    for (int j = 0; j < 4; ++j) { a[j] *= s; b[j] *= s; }
    ((f32x4*)p)[lane] = a;
    ((f32x4*)p)[lane + 64] = b;
}

extern "C" void kernel_launch(void* const* d_in, const int* in_sizes, int n_in,
                              void* d_out, int out_size, void* d_ws, size_t ws_size,
                              hipStream_t stream) {
    (void)in_sizes; (void)n_in; (void)out_size; (void)ws_size;
    const float* x  = (const float*)d_in[0];
    const float* W1 = (const float*)d_in[1];
    const float* r1 = (const float*)d_in[2];
    const float* b1 = (const float*)d_in[3];
    const float* W2 = (const float*)d_in[4];
    const float* r2 = (const float*)d_in[5];
    const float* b2 = (const float*)d_in[6];
    const int* src = (const int*)d_in[7];
    const int* dst = (const int*)d_in[8];
    const int* et  = (const int*)d_in[9];
    float* out = (float*)d_out;

    char* w = (char*)d_ws;
    auto take = [&](size_t bytes) {
        char* p = w;
        w += (bytes + 255) & ~(size_t)255;
        return p;
    };
    int*    cnt   = (int*)   take((size_t)RR * NN * 4);
    __bf16* x_hi  = (__bf16*)take((size_t)NN * CIN * 2);
    __bf16* x_lo  = (__bf16*)take((size_t)NN * CIN * 2);
    __bf16* h_hi  = (__bf16*)take((size_t)NN * CHID * 2);
    __bf16* h_lo  = (__bf16*)take((size_t)NN * CHID * 2);
    __bf16* W1t_h = (__bf16*)take((size_t)RR * CIN * CHID * 2);
    __bf16* W1t_l = (__bf16*)take((size_t)RR * CIN * CHID * 2);
    __bf16* W2t_h = (__bf16*)take((size_t)RR * CHID * COUT * 2);
    __bf16* W2t_l = (__bf16*)take((size_t)RR * CHID * COUT * 2);
    __bf16* r1t_h = (__bf16*)take((size_t)CIN * CHID * 2);
    __bf16* r1t_l = (__bf16*)take((size_t)CIN * CHID * 2);
    __bf16* r2t_h = (__bf16*)take((size_t)CHID * COUT * 2);
    __bf16* r2t_l = (__bf16*)take((size_t)CHID * COUT * 2);
    float*  xW    = (float*) take((size_t)NN * COUT * 4);   // reused both layers
    float*  acc1  = (float*) take((size_t)NN * CHID * 4);   // layer-1 accumulator

    hipMemsetAsync(cnt, 0, (size_t)RR * NN * 4, stream);
    hipMemsetAsync(acc1, 0, (size_t)NN * CHID * 4, stream);
    hipMemsetAsync(out, 0, (size_t)NN * COUT * 4, stream);  // layer-2 accumulator

    cvt_split<<<(NN * CIN / 4 + 255) / 256, 256, 0, stream>>>(x, x_hi, x_lo, NN * CIN / 4);
    wprep<CHID><<<dim3((CIN * CHID + 255) / 256, 1, RR), 256, 0, stream>>>(W1, W1t_h, W1t_l, CIN);
    wprep<CHID><<<dim3((CIN * CHID + 255) / 256, 1, 1),  256, 0, stream>>>(r1, r1t_h, r1t_l, CIN);
    wprep<COUT><<<dim3((CHID * COUT + 255) / 256, 1, RR), 256, 0, stream>>>(W2, W2t_h, W2t_l, CHID);
    wprep<COUT><<<dim3((CHID * COUT + 255) / 256, 1, 1),  256, 0, stream>>>(r2, r2t_h, r2t_l, CHID);
    count_edges<<<(EE + 255) / 256, 256, 0, stream>>>(et, dst, cnt);

    const int MT = (NN + 127) / 128;  // 391 M-tiles

    // ---- layer 1: per-relation pretransform + scatter, then root/bias/relu finish -> h ----
    for (int rel = 0; rel < RR; ++rel) {
        gemm_split<CIN, CHID, 0><<<dim3(MT, CHID / 128), 256, 0, stream>>>(
            x_hi, x_lo, W1t_h + (size_t)rel * CIN * CHID, W1t_l + (size_t)rel * CIN * CHID,
            xW, nullptr, nullptr, nullptr, nullptr, NN);
        scatter_edges<CHID><<<4096, 256, 0, stream>>>(xW, src, dst, et, cnt, acc1, rel);
    }
    gemm_split<CIN, CHID, 1><<<dim3(MT, CHID / 128), 256, 0, stream>>>(
        x_hi, x_lo, r1t_h, r1t_l, nullptr, acc1, b1, h_hi, h_lo, NN);

    // ---- layer 2: same, accumulate into d_out, finish in-place ----
    for (int rel = 0; rel < RR; ++rel) {
        gemm_split<CHID, COUT, 0><<<dim3(MT, COUT / 128), 256, 0, stream>>>(
            h_hi, h_lo, W2t_h + (size_t)rel * CHID * COUT, W2t_l + (size_t)rel * CHID * COUT,
            xW, nullptr, nullptr, nullptr, nullptr, NN);
        scatter_edges<COUT><<<4096, 256, 0, stream>>>(xW, src, dst, et, cnt, out, rel);
    }
    gemm_split<CHID, COUT, 2><<<dim3(MT, COUT / 128), 256, 0, stream>>>(
        h_hi, h_lo, r2t_h, r2t_l, out, out, b2, nullptr, nullptr, NN);

    l2norm<<<(NN + 3) / 4, 256, 0, stream>>>(out);
}

// Round 2
// 2173.659 us; speedup vs baseline: 4.4450x; 4.4450x over previous
//
#include <hip/hip_runtime.h>
#include <hip/hip_bf16.h>
#include <stdint.h>

#define NN   50000
#define EE   800000
#define RR   8
#define CIN  512
#define CHID 256
#define COUT 512
#define SEGS (RR * NN)

typedef __bf16 bf16x8 __attribute__((ext_vector_type(8)));
typedef __bf16 bf16x4 __attribute__((ext_vector_type(4)));
typedef float  f32x4  __attribute__((ext_vector_type(4)));

constexpr int SCAN_BS = 256, SCAN_ITEMS = 4, SCAN_CHUNK = SCAN_BS * SCAN_ITEMS; // 1024
constexpr int SCAN_NB = (SEGS + SCAN_CHUNK - 1) / SCAN_CHUNK;                   // 391

__device__ __forceinline__ f32x4 mfma_bf16(bf16x8 a, bf16x8 b, f32x4 c) {
    return __builtin_amdgcn_mfma_f32_16x16x32_bf16(a, b, c, 0, 0, 0);
}

__device__ __forceinline__ void gload_lds16(const void* g, void* l) {
    __builtin_amdgcn_global_load_lds((const __attribute__((address_space(1))) void*)g,
                                     (__attribute__((address_space(3))) void*)l, 16, 0, 0);
}

// ---------------- prep: split fp32 -> (hi, lo) bf16 ----------------
__global__ void cvt_split(const float* __restrict__ in, __bf16* __restrict__ hi,
                          __bf16* __restrict__ lo, int n4) {
    int i = blockIdx.x * blockDim.x + threadIdx.x;
    if (i >= n4) return;
    f32x4 v = ((const f32x4*)in)[i];
    bf16x4 h, l;
#pragma unroll
    for (int j = 0; j < 4; ++j) {
        __bf16 hj = (__bf16)v[j];
        h[j] = hj;
        l[j] = (__bf16)(v[j] - (float)hj);
    }
    ((bf16x4*)hi)[i] = h;
    ((bf16x4*)lo)[i] = l;
}

// transpose + split: W[r][K][NC] -> Wt[r][NC][K] (hi, lo)
template <int NC>
__global__ void wprep(const float* __restrict__ W, __bf16* __restrict__ hi,
                      __bf16* __restrict__ lo, int K) {
    int r = blockIdx.z;
    int idx = blockIdx.x * blockDim.x + threadIdx.x;
    if (idx >= K * NC) return;
    int k = idx / NC, nc = idx % NC;
    float v = W[(size_t)r * K * NC + idx];
    __bf16 h = (__bf16)v;
    size_t o = (size_t)r * NC * K + (size_t)nc * K + k;
    hi[o] = h;
    lo[o] = (__bf16)(v - (float)h);
}

// ---------------- per-(rel,dst) edge counts ----------------
__global__ void count_edges(const int* __restrict__ et, const int* __restrict__ dst,
                            int* __restrict__ cnt) {
    int e = blockIdx.x * blockDim.x + threadIdx.x;
    if (e < EE) atomicAdd(&cnt[et[e] * NN + dst[e]], 1);
}

// ---------------- exclusive scan of cnt[SEGS] -> cursor (3-pass) ----------------
__global__ void scan_partial(const int* __restrict__ cnt, int* __restrict__ bsum) {
    __shared__ int lds[SCAN_BS];
    const int b = blockIdx.x, t = threadIdx.x;
    const int base = b * SCAN_CHUNK + t * SCAN_ITEMS;
    int s = 0;
#pragma unroll
    for (int j = 0; j < SCAN_ITEMS; ++j) {
        int i = base + j;
        if (i < SEGS) s += cnt[i];
    }
    lds[t] = s;
    __syncthreads();
    for (int off = SCAN_BS / 2; off > 0; off >>= 1) {
        if (t < off) lds[t] += lds[t + off];
        __syncthreads();
    }
    if (t == 0) bsum[b] = lds[0];
}

__global__ void scan_bsum(int* __restrict__ bsum) {
    __shared__ int lds[512];
    const int t = threadIdx.x;
    const int v = (t < SCAN_NB) ? bsum[t] : 0;
    lds[t] = v;
    __syncthreads();
    for (int off = 1; off < 512; off <<= 1) {
        int x = (t >= off) ? lds[t - off] : 0;
        __syncthreads();
        lds[t] += x;
        __syncthreads();
    }
    if (t < SCAN_NB) bsum[t] = lds[t] - v;   // exclusive
}

__global__ void scan_final(const int* __restrict__ cnt, const int* __restrict__ bsum,
                           int* __restrict__ cursor) {
    __shared__ int lds[SCAN_BS];
    const int b = blockIdx.x, t = threadIdx.x;
    const int base = b * SCAN_CHUNK + t * SCAN_ITEMS;
    int v[SCAN_ITEMS];
    int s = 0;
#pragma unroll
    for (int j = 0; j < SCAN_ITEMS; ++j) {
        int i = base + j;
        v[j] = (i < SEGS) ? cnt[i] : 0;
        s += v[j];
    }
    lds[t] = s;
    __syncthreads();
    for (int off = 1; off < SCAN_BS; off <<= 1) {
        int x = (t >= off) ? lds[t - off] : 0;
        __syncthreads();
        lds[t] += x;
        __syncthreads();
    }
    int run = lds[t] - s + bsum[b];          // exclusive prefix for this thread's chunk
#pragma unroll
    for (int j = 0; j < SCAN_ITEMS; ++j) {
        int i = base + j;
        if (i < SEGS) cursor[i] = run;
        run += v[j];
    }
}

// ---------------- bucket fill: esrc sorted by (rel,dst) segment ----------------
// after this pass, cursor[s] == segment END offset (begin = end - cnt[s])
__global__ void bucket_fill(const int* __restrict__ src, const int* __restrict__ dst,
                            const int* __restrict__ et, int* __restrict__ cursor,
                            int* __restrict__ esrc) {
    int e = blockIdx.x * blockDim.x + threadIdx.x;
    if (e < EE) {
        int s = et[e] * NN + dst[e];
        int pos = atomicAdd(&cursor[s], 1);
        esrc[pos] = src[e];
    }
}

// ---------------- split-bf16 MFMA GEMM, 128x128 tile, BK=64 ----------------
// C[M,NC] = (Ah+Al)[M,K] @ (Bh+Bl)^T[NC,K]^T   (3-term split product)
// EPI 0: store fp32 C
// EPI 1: v += Cin + bias; relu; store (hi,lo) bf16 to Oh/Ol   (layer-1 finish -> h)
// EPI 2: v += Cin + bias; store fp32 C                        (layer-2 finish)
template <int K, int NC, int EPI>
__global__ __launch_bounds__(256, 2) void gemm_split(
    const __bf16* __restrict__ Ah, const __bf16* __restrict__ Al,
    const __bf16* __restrict__ Bh, const __bf16* __restrict__ Bl,
    float* __restrict__ C, const float* __restrict__ Cin,
    const float* __restrict__ bias,
    __bf16* __restrict__ Oh, __bf16* __restrict__ Ol, int M) {
    __shared__ __bf16 lds[32768];          // 64 KB: Ah|Al|Bh|Bl, each [128][64]
    __bf16* sAh = lds;
    __bf16* sAl = lds + 8192;
    __bf16* sBh = lds + 16384;
    __bf16* sBl = lds + 24576;

    const int tid  = threadIdx.x;
    const int lane = tid & 63;
    const int wid  = tid >> 6;
    const int wm   = wid >> 1, wn = wid & 1;
    const int row0 = blockIdx.x * 128;
    const int col0 = blockIdx.y * 128;

    f32x4 acc[4][4] = {};

    for (int ks = 0; ks < K / 64; ++ks) {
        const int k0 = ks * 64;
#pragma unroll
        for (int i = 0; i < 4; ++i) {
            int flat = i * 256 + tid;          // 1024 chunks of 8 bf16
            int rr = flat >> 3;
            int kc = (flat & 7) * 8;
            int ra = row0 + rr;
            ra = ra < M ? ra : M - 1;          // clamp tail rows (masked at store)
            size_t ga = (size_t)ra * K + k0 + kc;
            size_t gb = (size_t)(col0 + rr) * K + k0 + kc;
            gload_lds16(Ah + ga, sAh + flat * 8);
            gload_lds16(Al + ga, sAl + flat * 8);
            gload_lds16(Bh + gb, sBh + flat * 8);
            gload_lds16(Bl + gb, sBl + flat * 8);
        }
        __syncthreads();
#pragma unroll
        for (int kk = 0; kk < 2; ++kk) {
            const int ko = kk * 32 + (lane >> 4) * 8;
            bf16x8 fah[4], fal[4], fbh[4], fbl[4];
#pragma unroll
            for (int m = 0; m < 4; ++m) {
                int ar = wm * 64 + m * 16 + (lane & 15);
                fah[m] = *(const bf16x8*)(sAh + ar * 64 + ko);
                fal[m] = *(const bf16x8*)(sAl + ar * 64 + ko);
            }
#pragma unroll
            for (int n = 0; n < 4; ++n) {
                int br = wn * 64 + n * 16 + (lane & 15);
                fbh[n] = *(const bf16x8*)(sBh + br * 64 + ko);
                fbl[n] = *(const bf16x8*)(sBl + br * 64 + ko);
            }
#pragma unroll
            for (int m = 0; m < 4; ++m)
#pragma unroll
                for (int n = 0; n < 4; ++n) {
                    acc[m][n] = mfma_bf16(fah[m], fbh[n], acc[m][n]);
                    acc[m][n] = mfma_bf16(fal[m], fbh[n], acc[m][n]);
                    acc[m][n] = mfma_bf16(fah[m], fbl[n], acc[m][n]);
                }
        }
        __syncthreads();
    }

#pragma unroll
    for (int m = 0; m < 4; ++m)
#pragma unroll
        for (int n = 0; n < 4; ++n)
#pragma unroll
            for (int q = 0; q < 4; ++q) {
                int row = row0 + wm * 64 + m * 16 + (lane >> 4) * 4 + q;
                int col = col0 + wn * 64 + n * 16 + (lane & 15);
                if (row < M) {
                    size_t o = (size_t)row * NC + col;
                    float v = acc[m][n][q];
                    if (EPI >= 1) v += Cin[o] + bias[col];
                    if (EPI == 1) {
                        v = fmaxf(v, 0.0f);
                        __bf16 h = (__bf16)v;
                        Oh[o] = h;
                        Ol[o] = (__bf16)(v - (float)h);
                    } else {
                        C[o] = v;
                    }
                }
            }
}

// ---------------- per-(rel,dst) owner-computes gather (NO atomics) ----------------
// one wave per dst node: acc[d] += (1/cnt) * sum_{e in seg(rel,d)} xW[esrc[e]]
template <int NC>
__global__ void gather_rel(const float* __restrict__ xW, const int* __restrict__ esrc,
                           const int* __restrict__ cursor, const int* __restrict__ cnt,
                           float* __restrict__ acc, int rel) {
    const int d = blockIdx.x * 4 + (threadIdx.x >> 6);
    if (d >= NN) return;
    const int lane = threadIdx.x & 63;
    const int s = rel * NN + d;
    const int n = cnt[s];
    if (n == 0) return;
    const int end = cursor[s];          // bucket_fill left cursor at segment END
    const int beg = end - n;
    const float inv = 1.0f / (float)n;
    f32x4 v0 = {};
    f32x4 v1 = {};
    for (int i = beg; i < end; ++i) {
        const f32x4* row = (const f32x4*)(xW + (size_t)esrc[i] * NC);
        v0 += row[lane];
        if (NC == 512) v1 += row[lane + 64];
    }
    f32x4* p = (f32x4*)(acc + (size_t)d * NC);
    p[lane] += v0 * inv;
    if (NC == 512) p[lane + 64] += v1 * inv;
}

// ---------------- row-wise L2 normalize (one wave per 512-col row) ----------------
__global__ void l2norm(float* __restrict__ out) {
    int row = blockIdx.x * 4 + (threadIdx.x >> 6);
    int lane = threadIdx.x & 63;
    if (row >= NN) return;
    float* p = out + (size_t)row * COUT;
    f32x4 a = ((const f32x4*)p)[lane];
    f32x4 b = ((const f32x4*)p)[lane + 64];
    float ss = a[0] * a[0] + a[1] * a[1] + a[2] * a[2] + a[3] * a[3] +
               b[0] * b[0] + b[1] * b[1] + b[2] * b[2] + b[3] * b[3];
#pragma unroll
    for (int m = 32; m >= 1; m >>= 1) ss += __shfl_xor(ss, m, 64);
    const float s = 1.0f / fmaxf(sqrtf(ss), 1e-12f);
#pragma unroll
    for (int j = 0; j < 4; ++j) { a[j] *= s; b[j] *= s; }
    ((f32x4*)p)[lane] = a;
    ((f32x4*)p)[lane + 64] = b;
}

extern "C" void kernel_launch(void* const* d_in, const int* in_sizes, int n_in,
                              void* d_out, int out_size, void* d_ws, size_t ws_size,
                              hipStream_t stream) {
    (void)in_sizes; (void)n_in; (void)out_size; (void)ws_size;
    const float* x  = (const float*)d_in[0];
    const float* W1 = (const float*)d_in[1];
    const float* r1 = (const float*)d_in[2];
    const float* b1 = (const float*)d_in[3];
    const float* W2 = (const float*)d_in[4];
    const float* r2 = (const float*)d_in[5];
    const float* b2 = (const float*)d_in[6];
    const int* src = (const int*)d_in[7];
    const int* dst = (const int*)d_in[8];
    const int* et  = (const int*)d_in[9];
    float* out = (float*)d_out;

    char* w = (char*)d_ws;
    auto take = [&](size_t bytes) {
        char* p = w;
        w += (bytes + 255) & ~(size_t)255;
        return p;
    };
    int*    cnt    = (int*)   take((size_t)SEGS * 4);
    int*    cursor = (int*)   take((size_t)SEGS * 4);
    int*    bsum   = (int*)   take((size_t)SCAN_NB * 4);
    int*    esrc   = (int*)   take((size_t)EE * 4);
    __bf16* x_hi  = (__bf16*)take((size_t)NN * CIN * 2);
    __bf16* x_lo  = (__bf16*)take((size_t)NN * CIN * 2);
    __bf16* h_hi  = (__bf16*)take((size_t)NN * CHID * 2);
    __bf16* h_lo  = (__bf16*)take((size_t)NN * CHID * 2);
    __bf16* W1t_h = (__bf16*)take((size_t)RR * CIN * CHID * 2);
    __bf16* W1t_l = (__bf16*)take((size_t)RR * CIN * CHID * 2);
    __bf16* W2t_h = (__bf16*)take((size_t)RR * CHID * COUT * 2);
    __bf16* W2t_l = (__bf16*)take((size_t)RR * CHID * COUT * 2);
    __bf16* r1t_h = (__bf16*)take((size_t)CIN * CHID * 2);
    __bf16* r1t_l = (__bf16*)take((size_t)CIN * CHID * 2);
    __bf16* r2t_h = (__bf16*)take((size_t)CHID * COUT * 2);
    __bf16* r2t_l = (__bf16*)take((size_t)CHID * COUT * 2);
    float*  xW    = (float*) take((size_t)NN * COUT * 4);   // reused both layers
    float*  acc1  = (float*) take((size_t)NN * CHID * 4);   // layer-1 accumulator

    hipMemsetAsync(cnt, 0, (size_t)SEGS * 4, stream);
    hipMemsetAsync(acc1, 0, (size_t)NN * CHID * 4, stream);
    hipMemsetAsync(out, 0, (size_t)NN * COUT * 4, stream);  // layer-2 accumulator

    cvt_split<<<(NN * CIN / 4 + 255) / 256, 256, 0, stream>>>(x, x_hi, x_lo, NN * CIN / 4);
    wprep<CHID><<<dim3((CIN * CHID + 255) / 256, 1, RR), 256, 0, stream>>>(W1, W1t_h, W1t_l, CIN);
    wprep<CHID><<<dim3((CIN * CHID + 255) / 256, 1, 1),  256, 0, stream>>>(r1, r1t_h, r1t_l, CIN);
    wprep<COUT><<<dim3((CHID * COUT + 255) / 256, 1, RR), 256, 0, stream>>>(W2, W2t_h, W2t_l, CHID);
    wprep<COUT><<<dim3((CHID * COUT + 255) / 256, 1, 1),  256, 0, stream>>>(r2, r2t_h, r2t_l, CHID);

    // counting sort: cnt -> exclusive scan -> bucket fill (cursor ends at segment END)
    count_edges<<<(EE + 255) / 256, 256, 0, stream>>>(et, dst, cnt);
    scan_partial<<<SCAN_NB, SCAN_BS, 0, stream>>>(cnt, bsum);
    scan_bsum<<<1, 512, 0, stream>>>(bsum);
    scan_final<<<SCAN_NB, SCAN_BS, 0, stream>>>(cnt, bsum, cursor);
    bucket_fill<<<(EE + 255) / 256, 256, 0, stream>>>(src, dst, et, cursor, esrc);

    const int MT = (NN + 127) / 128;  // 391 M-tiles

    // ---- layer 1: per-relation pretransform + gather, then root/bias/relu finish -> h ----
    for (int rel = 0; rel < RR; ++rel) {
        gemm_split<CIN, CHID, 0><<<dim3(MT, CHID / 128), 256, 0, stream>>>(
            x_hi, x_lo, W1t_h + (size_t)rel * CIN * CHID, W1t_l + (size_t)rel * CIN * CHID,
            xW, nullptr, nullptr, nullptr, nullptr, NN);
        gather_rel<CHID><<<(NN + 3) / 4, 256, 0, stream>>>(xW, esrc, cursor, cnt, acc1, rel);
    }
    gemm_split<CIN, CHID, 1><<<dim3(MT, CHID / 128), 256, 0, stream>>>(
        x_hi, x_lo, r1t_h, r1t_l, nullptr, acc1, b1, h_hi, h_lo, NN);

    // ---- layer 2: same, accumulate into d_out, finish in-place ----
    for (int rel = 0; rel < RR; ++rel) {
        gemm_split<CHID, COUT, 0><<<dim3(MT, COUT / 128), 256, 0, stream>>>(
            h_hi, h_lo, W2t_h + (size_t)rel * CHID * COUT, W2t_l + (size_t)rel * CHID * COUT,
            xW, nullptr, nullptr, nullptr, nullptr, NN);
        gather_rel<COUT><<<(NN + 3) / 4, 256, 0, stream>>>(xW, esrc, cursor, cnt, out, rel);
    }
    gemm_split<CHID, COUT, 2><<<dim3(MT, COUT / 128), 256, 0, stream>>>(
        h_hi, h_lo, r2t_h, r2t_l, out, out, b2, nullptr, nullptr, NN);

    l2norm<<<(NN + 3) / 4, 256, 0, stream>>>(out);
}

// Round 3
// 1731.332 us; speedup vs baseline: 5.5807x; 1.2555x over previous
//
#include <hip/hip_runtime.h>
#include <hip/hip_bf16.h>
#include <stdint.h>

#define NN   50000
#define EE   800000
#define RR   8
#define CIN  512
#define CHID 256
#define COUT 512
#define SEGS (RR * NN)
#define MHALF 25000
#define K2   2304              // 8*CHID + CHID (relations + root)
#define K2S  2048              // split point: below = G2, above = h

typedef __bf16 bf16x8 __attribute__((ext_vector_type(8)));
typedef __bf16 bf16x4 __attribute__((ext_vector_type(4)));
typedef float  f32x4  __attribute__((ext_vector_type(4)));

constexpr int SCAN_BS = 256, SCAN_ITEMS = 4, SCAN_CHUNK = SCAN_BS * SCAN_ITEMS; // 1024
constexpr int SCAN_NB = (SEGS + SCAN_CHUNK - 1) / SCAN_CHUNK;                   // 391

__device__ __forceinline__ f32x4 mfma_bf16(bf16x8 a, bf16x8 b, f32x4 c) {
    return __builtin_amdgcn_mfma_f32_16x16x32_bf16(a, b, c, 0, 0, 0);
}

__device__ __forceinline__ void gload_lds16(const void* g, void* l) {
    __builtin_amdgcn_global_load_lds((const __attribute__((address_space(1))) void*)g,
                                     (__attribute__((address_space(3))) void*)l, 16, 0, 0);
}

// ---------------- prep: split fp32 -> (hi, lo) bf16 ----------------
__global__ void cvt_split(const float* __restrict__ in, __bf16* __restrict__ hi,
                          __bf16* __restrict__ lo, int n4) {
    int i = blockIdx.x * blockDim.x + threadIdx.x;
    if (i >= n4) return;
    f32x4 v = ((const f32x4*)in)[i];
    bf16x4 h, l;
#pragma unroll
    for (int j = 0; j < 4; ++j) {
        __bf16 hj = (__bf16)v[j];
        h[j] = hj;
        l[j] = (__bf16)(v[j] - (float)hj);
    }
    ((bf16x4*)hi)[i] = h;
    ((bf16x4*)lo)[i] = l;
}

// transpose + split weights into B^T layout: dst[rel*relstride + col*Ktot + koffbase + rel*koffstride + k]
__global__ void wprep(const float* __restrict__ W, __bf16* __restrict__ hi,
                      __bf16* __restrict__ lo, int K0, int NC, int Ktot,
                      int koffbase, int koffstride, int relstride) {
    int r = blockIdx.z;
    int idx = blockIdx.x * blockDim.x + threadIdx.x;
    if (idx >= K0 * NC) return;
    int k = idx / NC, c = idx % NC;
    float v = W[(size_t)r * K0 * NC + idx];
    __bf16 h = (__bf16)v;
    size_t o = (size_t)r * relstride + (size_t)c * Ktot + koffbase + r * koffstride + k;
    hi[o] = h;
    lo[o] = (__bf16)(v - (float)h);
}

// ---------------- per-(rel,dst) edge counts ----------------
__global__ void count_edges(const int* __restrict__ et, const int* __restrict__ dst,
                            int* __restrict__ cnt) {
    int e = blockIdx.x * blockDim.x + threadIdx.x;
    if (e < EE) atomicAdd(&cnt[et[e] * NN + dst[e]], 1);
}

// ---------------- exclusive scan of cnt[SEGS] -> cursor (3-pass) ----------------
__global__ void scan_partial(const int* __restrict__ cnt, int* __restrict__ bsum) {
    __shared__ int lds[SCAN_BS];
    const int b = blockIdx.x, t = threadIdx.x;
    const int base = b * SCAN_CHUNK + t * SCAN_ITEMS;
    int s = 0;
#pragma unroll
    for (int j = 0; j < SCAN_ITEMS; ++j) {
        int i = base + j;
        if (i < SEGS) s += cnt[i];
    }
    lds[t] = s;
    __syncthreads();
    for (int off = SCAN_BS / 2; off > 0; off >>= 1) {
        if (t < off) lds[t] += lds[t + off];
        __syncthreads();
    }
    if (t == 0) bsum[b] = lds[0];
}

__global__ void scan_bsum(int* __restrict__ bsum) {
    __shared__ int lds[512];
    const int t = threadIdx.x;
    const int v = (t < SCAN_NB) ? bsum[t] : 0;
    lds[t] = v;
    __syncthreads();
    for (int off = 1; off < 512; off <<= 1) {
        int x = (t >= off) ? lds[t - off] : 0;
        __syncthreads();
        lds[t] += x;
        __syncthreads();
    }
    if (t < SCAN_NB) bsum[t] = lds[t] - v;   // exclusive
}

__global__ void scan_final(const int* __restrict__ cnt, const int* __restrict__ bsum,
                           int* __restrict__ cursor) {
    __shared__ int lds[SCAN_BS];
    const int b = blockIdx.x, t = threadIdx.x;
    const int base = b * SCAN_CHUNK + t * SCAN_ITEMS;
    int v[SCAN_ITEMS];
    int s = 0;
#pragma unroll
    for (int j = 0; j < SCAN_ITEMS; ++j) {
        int i = base + j;
        v[j] = (i < SEGS) ? cnt[i] : 0;
        s += v[j];
    }
    lds[t] = s;
    __syncthreads();
    for (int off = 1; off < SCAN_BS; off <<= 1) {
        int x = (t >= off) ? lds[t - off] : 0;
        __syncthreads();
        lds[t] += x;
        __syncthreads();
    }
    int run = lds[t] - s + bsum[b];
#pragma unroll
    for (int j = 0; j < SCAN_ITEMS; ++j) {
        int i = base + j;
        if (i < SEGS) cursor[i] = run;
        run += v[j];
    }
}

// ---------------- bucket fill: esrc sorted by (rel,dst) segment ----------------
// after this pass, cursor[s] == segment END offset (begin = end - cnt[s])
__global__ void bucket_fill(const int* __restrict__ src, const int* __restrict__ dst,
                            const int* __restrict__ et, int* __restrict__ cursor,
                            int* __restrict__ esrc) {
    int e = blockIdx.x * blockDim.x + threadIdx.x;
    if (e < EE) {
        int s = et[e] * NN + dst[e];
        int pos = atomicAdd(&cursor[s], 1);
        esrc[pos] = src[e];
    }
}

// ---------------- split-bf16 MFMA GEMM, 128x128 tile, BK=32, dual A-source ----------------
// C[M,NC] = A[M,K] @ B^T[NC,K]^T  with A = [A1 (K<K1) | A2 (K>=K1)], all hi/lo split.
// 3-term split product per fragment. XCD-swizzled block mapping for A-panel L2 reuse.
// EPI 0: C[o] = v            (xW)
// EPI 3: C[o] = v + bias[c]  (root-first h_pre / final out)
template <int K, int K1, int SA1, int SA2, int NC, int EPI>
__global__ __launch_bounds__(256, 4) void gemm_split(
    const __bf16* __restrict__ A1h, const __bf16* __restrict__ A1l,
    const __bf16* __restrict__ A2h, const __bf16* __restrict__ A2l,
    const __bf16* __restrict__ Bh, const __bf16* __restrict__ Bl,
    float* __restrict__ C, const float* __restrict__ bias, int M) {
    __shared__ __bf16 lds[16384];          // 32 KB: Ah|Al|Bh|Bl, each [128][32]
    __bf16* sAh = lds;
    __bf16* sAl = lds + 4096;
    __bf16* sBh = lds + 8192;
    __bf16* sBl = lds + 12288;

    constexpr int NT = NC / 128;           // 2 or 4 col-tiles

    // bijective XCD-aware swizzle (m204): same-XCD-consecutive blocks share an A panel
    const int nwg = gridDim.x;
    const int orig = blockIdx.x;
    const int q = nwg >> 3, r8 = nwg & 7;
    const int xcd = orig & 7, lin = orig >> 3;
    const int wg = (xcd < r8 ? xcd * (q + 1) : r8 * (q + 1) + (xcd - r8) * q) + lin;
    const int mtile = wg / NT, ntile = wg % NT;

    const int tid  = threadIdx.x;
    const int lane = tid & 63;
    const int wid  = tid >> 6;
    const int wm   = wid >> 1, wn = wid & 1;
    const int row0 = mtile * 128;
    const int col0 = ntile * 128;

    f32x4 acc[4][4] = {};

    for (int ks = 0; ks < K / 32; ++ks) {
        const int k0 = ks * 32;
        const bool useA2 = (K1 < K) && (k0 >= K1);
#pragma unroll
        for (int i = 0; i < 2; ++i) {
            int flat = i * 256 + tid;          // 512 chunks of 8 bf16 per buffer
            int rr = flat >> 2;
            int kc = (flat & 3) * 8;
            int ra = row0 + rr;
            ra = ra < M ? ra : M - 1;          // clamp tail rows (masked at store)
            const __bf16* gah = useA2 ? A2h + (size_t)ra * SA2 + (k0 - K1 + kc)
                                      : A1h + (size_t)ra * SA1 + (k0 + kc);
            const __bf16* gal = useA2 ? A2l + (size_t)ra * SA2 + (k0 - K1 + kc)
                                      : A1l + (size_t)ra * SA1 + (k0 + kc);
            size_t gb = (size_t)(col0 + rr) * K + k0 + kc;
            gload_lds16(gah, sAh + flat * 8);
            gload_lds16(gal, sAl + flat * 8);
            gload_lds16(Bh + gb, sBh + flat * 8);
            gload_lds16(Bl + gb, sBl + flat * 8);
        }
        __syncthreads();
        {
            const int ko = (lane >> 4) * 8;
            bf16x8 fah[4], fal[4], fbh[4], fbl[4];
#pragma unroll
            for (int m = 0; m < 4; ++m) {
                int ar = wm * 64 + m * 16 + (lane & 15);
                fah[m] = *(const bf16x8*)(sAh + ar * 32 + ko);
                fal[m] = *(const bf16x8*)(sAl + ar * 32 + ko);
            }
#pragma unroll
            for (int n = 0; n < 4; ++n) {
                int br = wn * 64 + n * 16 + (lane & 15);
                fbh[n] = *(const bf16x8*)(sBh + br * 32 + ko);
                fbl[n] = *(const bf16x8*)(sBl + br * 32 + ko);
            }
#pragma unroll
            for (int m = 0; m < 4; ++m)
#pragma unroll
                for (int n = 0; n < 4; ++n) {
                    acc[m][n] = mfma_bf16(fah[m], fbh[n], acc[m][n]);
                    acc[m][n] = mfma_bf16(fal[m], fbh[n], acc[m][n]);
                    acc[m][n] = mfma_bf16(fah[m], fbl[n], acc[m][n]);
                }
        }
        __syncthreads();
    }

#pragma unroll
    for (int m = 0; m < 4; ++m)
#pragma unroll
        for (int n = 0; n < 4; ++n)
#pragma unroll
            for (int q2 = 0; q2 < 4; ++q2) {
                int row = row0 + wm * 64 + m * 16 + (lane >> 4) * 4 + q2;
                int col = col0 + wn * 64 + n * 16 + (lane & 15);
                if (row < M) {
                    size_t o = (size_t)row * NC + col;
                    float v = acc[m][n][q2];
                    if (EPI == 3) v += bias[col];
                    C[o] = v;
                }
            }
}

// ---------------- L1 gather: h_pre[d] += (1/cnt) * sum_{seg(rel,d)} xW[esrc] ----------------
__global__ void gather_l1(const float* __restrict__ xW, const int* __restrict__ esrc,
                          const int* __restrict__ cursor, const int* __restrict__ cnt,
                          float* __restrict__ h_pre, int rel) {
    const int d = blockIdx.x * 4 + (threadIdx.x >> 6);
    if (d >= NN) return;
    const int lane = threadIdx.x & 63;
    const int s = rel * NN + d;
    const int n = cnt[s];
    if (n == 0) return;
    const int end = cursor[s];
    const int beg = end - n;
    const float inv = 1.0f / (float)n;
    f32x4 v0 = {};
    for (int i = beg; i < end; ++i)
        v0 += ((const f32x4*)(xW + (size_t)esrc[i] * CHID))[lane];
    ((f32x4*)(h_pre + (size_t)d * CHID))[lane] += v0 * inv;
}

// ---------------- finish1: h = relu(h_pre) -> split bf16 hi/lo ----------------
__global__ void finish1(const float* __restrict__ h_pre, __bf16* __restrict__ hh,
                        __bf16* __restrict__ hl) {
    int i = blockIdx.x * blockDim.x + threadIdx.x;
    if (i >= NN * CHID / 4) return;
    f32x4 v = ((const f32x4*)h_pre)[i];
    bf16x4 a, b;
#pragma unroll
    for (int j = 0; j < 4; ++j) {
        float x = fmaxf(v[j], 0.0f);
        __bf16 h = (__bf16)x;
        a[j] = h;
        b[j] = (__bf16)(x - (float)h);
    }
    ((bf16x4*)hh)[i] = a;
    ((bf16x4*)hl)[i] = b;
}

// ---------------- L2 gather-aggregate: G2[dloc, rel*256+c] = mean_{seg(rel,d)} h[src,c] ----------------
// one wave per (rel, dloc) segment; nontemporal stores keep h L3-resident
__global__ void gather_g2(const __bf16* __restrict__ hh, const __bf16* __restrict__ hl,
                          const int* __restrict__ esrc, const int* __restrict__ cursor,
                          const int* __restrict__ cnt, __bf16* __restrict__ G2h,
                          __bf16* __restrict__ G2l, int half) {
    const int sidx = blockIdx.x * 4 + (threadIdx.x >> 6);
    if (sidx >= RR * MHALF) return;
    const int lane = threadIdx.x & 63;
    const int rel = sidx / MHALF;
    const int dloc = sidx % MHALF;
    const int d = half * MHALF + dloc;
    const int s = rel * NN + d;
    const int n = cnt[s];
    f32x4 v = {};
    if (n > 0) {
        const int end = cursor[s];
        for (int i = end - n; i < end; ++i) {
            const size_t ro = (size_t)esrc[i] * CHID + lane * 4;
            bf16x4 a = *(const bf16x4*)(hh + ro);
            bf16x4 b = *(const bf16x4*)(hl + ro);
#pragma unroll
            for (int j = 0; j < 4; ++j) v[j] += (float)a[j] + (float)b[j];
        }
        const float inv = 1.0f / (float)n;
#pragma unroll
        for (int j = 0; j < 4; ++j) v[j] *= inv;
    }
    union { __bf16 b[4]; unsigned long long u; } ph, pl;
#pragma unroll
    for (int j = 0; j < 4; ++j) {
        __bf16 h = (__bf16)v[j];
        ph.b[j] = h;
        pl.b[j] = (__bf16)(v[j] - (float)h);
    }
    const size_t o = (size_t)dloc * K2S + rel * CHID + lane * 4;
    __builtin_nontemporal_store(ph.u, (unsigned long long*)(G2h + o));
    __builtin_nontemporal_store(pl.u, (unsigned long long*)(G2l + o));
}

// ---------------- row-wise L2 normalize (one wave per 512-col row) ----------------
__global__ void l2norm(float* __restrict__ out) {
    int row = blockIdx.x * 4 + (threadIdx.x >> 6);
    int lane = threadIdx.x & 63;
    if (row >= NN) return;
    float* p = out + (size_t)row * COUT;
    f32x4 a = ((const f32x4*)p)[lane];
    f32x4 b = ((const f32x4*)p)[lane + 64];
    float ss = a[0] * a[0] + a[1] * a[1] + a[2] * a[2] + a[3] * a[3] +
               b[0] * b[0] + b[1] * b[1] + b[2] * b[2] + b[3] * b[3];
#pragma unroll
    for (int m = 32; m >= 1; m >>= 1) ss += __shfl_xor(ss, m, 64);
    const float s = 1.0f / fmaxf(sqrtf(ss), 1e-12f);
#pragma unroll
    for (int j = 0; j < 4; ++j) { a[j] *= s; b[j] *= s; }
    ((f32x4*)p)[lane] = a;
    ((f32x4*)p)[lane + 64] = b;
}

extern "C" void kernel_launch(void* const* d_in, const int* in_sizes, int n_in,
                              void* d_out, int out_size, void* d_ws, size_t ws_size,
                              hipStream_t stream) {
    (void)in_sizes; (void)n_in; (void)out_size; (void)ws_size;
    const float* x  = (const float*)d_in[0];
    const float* W1 = (const float*)d_in[1];
    const float* r1 = (const float*)d_in[2];
    const float* b1 = (const float*)d_in[3];
    const float* W2 = (const float*)d_in[4];
    const float* r2 = (const float*)d_in[5];
    const float* b2 = (const float*)d_in[6];
    const int* src = (const int*)d_in[7];
    const int* dst = (const int*)d_in[8];
    const int* et  = (const int*)d_in[9];
    float* out = (float*)d_out;

    char* w = (char*)d_ws;
    auto take = [&](size_t bytes) {
        char* p = w;
        w += (bytes + 255) & ~(size_t)255;
        return p;
    };
    int*    cnt    = (int*)   take((size_t)SEGS * 4);
    int*    cursor = (int*)   take((size_t)SEGS * 4);
    int*    bsum   = (int*)   take((size_t)SCAN_NB * 4);
    int*    esrc   = (int*)   take((size_t)EE * 4);
    __bf16* x_hi  = (__bf16*)take((size_t)NN * CIN * 2);
    __bf16* x_lo  = (__bf16*)take((size_t)NN * CIN * 2);
    __bf16* hh    = (__bf16*)take((size_t)NN * CHID * 2);
    __bf16* hl    = (__bf16*)take((size_t)NN * CHID * 2);
    __bf16* W1t_h = (__bf16*)take((size_t)RR * CIN * CHID * 2);
    __bf16* W1t_l = (__bf16*)take((size_t)RR * CIN * CHID * 2);
    __bf16* r1t_h = (__bf16*)take((size_t)CIN * CHID * 2);
    __bf16* r1t_l = (__bf16*)take((size_t)CIN * CHID * 2);
    __bf16* W2c_h = (__bf16*)take((size_t)COUT * K2 * 2);   // [512 cols][2304] catted rels+root
    __bf16* W2c_l = (__bf16*)take((size_t)COUT * K2 * 2);
    // arena: reused across phases. L1: xW (51.2 MB) + h_pre (51.2 MB). L2: G2 hi/lo (204.8 MB).
    char* arena = take((size_t)MHALF * K2S * 2 * 2);
    float*  xW    = (float*)arena;                               // [50000][256] fp32
    float*  h_pre = (float*)(arena + (size_t)NN * CHID * 4);     // [50000][256] fp32
    __bf16* G2h   = (__bf16*)arena;                              // [25000][2048]
    __bf16* G2l   = (__bf16*)(arena + (size_t)MHALF * K2S * 2);

    hipMemsetAsync(cnt, 0, (size_t)SEGS * 4, stream);

    cvt_split<<<(NN * CIN / 4 + 255) / 256, 256, 0, stream>>>(x, x_hi, x_lo, NN * CIN / 4);
    // W1[r][512][256] -> W1t[r][256][512]
    wprep<<<dim3((CIN * CHID + 255) / 256, 1, RR), 256, 0, stream>>>(
        W1, W1t_h, W1t_l, CIN, CHID, CIN, 0, 0, CIN * CHID);
    wprep<<<dim3((CIN * CHID + 255) / 256, 1, 1), 256, 0, stream>>>(
        r1, r1t_h, r1t_l, CIN, CHID, CIN, 0, 0, 0);
    // W2[r][256][512] -> W2cat[512][r*256 + k];  root2 -> W2cat[512][2048 + k]
    wprep<<<dim3((CHID * COUT + 255) / 256, 1, RR), 256, 0, stream>>>(
        W2, W2c_h, W2c_l, CHID, COUT, K2, 0, CHID, 0);
    wprep<<<dim3((CHID * COUT + 255) / 256, 1, 1), 256, 0, stream>>>(
        r2, W2c_h, W2c_l, CHID, COUT, K2, K2S, 0, 0);

    // counting sort of edges by (rel,dst)
    count_edges<<<(EE + 255) / 256, 256, 0, stream>>>(et, dst, cnt);
    scan_partial<<<SCAN_NB, SCAN_BS, 0, stream>>>(cnt, bsum);
    scan_bsum<<<1, 512, 0, stream>>>(bsum);
    scan_final<<<SCAN_NB, SCAN_BS, 0, stream>>>(cnt, bsum, cursor);
    bucket_fill<<<(EE + 255) / 256, 256, 0, stream>>>(src, dst, et, cursor, esrc);

    const int MT1 = (NN + 127) / 128;     // 391
    const int MT2 = (MHALF + 127) / 128;  // 196

    // ---- layer 1: root-first, then per-relation transform + gather-RMW ----
    gemm_split<CIN, CIN, CIN, CIN, CHID, 3><<<MT1 * 2, 256, 0, stream>>>(
        x_hi, x_lo, x_hi, x_lo, r1t_h, r1t_l, h_pre, b1, NN);
    for (int rel = 0; rel < RR; ++rel) {
        gemm_split<CIN, CIN, CIN, CIN, CHID, 0><<<MT1 * 2, 256, 0, stream>>>(
            x_hi, x_lo, x_hi, x_lo,
            W1t_h + (size_t)rel * CIN * CHID, W1t_l + (size_t)rel * CIN * CHID,
            xW, nullptr, NN);
        gather_l1<<<(NN + 3) / 4, 256, 0, stream>>>(xW, esrc, cursor, cnt, h_pre, rel);
    }
    finish1<<<(NN * CHID / 4 + 255) / 256, 256, 0, stream>>>(h_pre, hh, hl);

    // ---- layer 2: aggregate-then-transform, two M-halves, single K=2304 GEMM each ----
    for (int half = 0; half < 2; ++half) {
        gather_g2<<<(RR * MHALF + 3) / 4, 256, 0, stream>>>(hh, hl, esrc, cursor, cnt,
                                                            G2h, G2l, half);
        gemm_split<K2, K2S, K2S, CHID, COUT, 3><<<MT2 * 4, 256, 0, stream>>>(
            G2h, G2l, hh + (size_t)half * MHALF * CHID, hl + (size_t)half * MHALF * CHID,
            W2c_h, W2c_l, out + (size_t)half * MHALF * COUT, b2, MHALF);
    }

    l2norm<<<(NN + 3) / 4, 256, 0, stream>>>(out);
}

// Round 4
// 1669.775 us; speedup vs baseline: 5.7864x; 1.0369x over previous
//
#include <hip/hip_runtime.h>
#include <hip/hip_bf16.h>
#include <stdint.h>

#define NN   50000
#define EE   800000
#define RR   8
#define CIN  512
#define CHID 256
#define COUT 512
#define SEGS (RR * NN)
#define MHALF 25000
#define K2   2304              // 8*CHID + CHID (relations + root)
#define K2S  2048              // split point: below = G2, above = h

typedef __bf16 bf16x8 __attribute__((ext_vector_type(8)));
typedef __bf16 bf16x4 __attribute__((ext_vector_type(4)));
typedef float  f32x4  __attribute__((ext_vector_type(4)));

constexpr int SCAN_BS = 256, SCAN_ITEMS = 4, SCAN_CHUNK = SCAN_BS * SCAN_ITEMS; // 1024
constexpr int SCAN_NB = (SEGS + SCAN_CHUNK - 1) / SCAN_CHUNK;                   // 391

__device__ __forceinline__ f32x4 mfma_bf16(bf16x8 a, bf16x8 b, f32x4 c) {
    return __builtin_amdgcn_mfma_f32_16x16x32_bf16(a, b, c, 0, 0, 0);
}

__device__ __forceinline__ void gload_lds16(const void* g, void* l) {
    __builtin_amdgcn_global_load_lds((const __attribute__((address_space(1))) void*)g,
                                     (__attribute__((address_space(3))) void*)l, 16, 0, 0);
}

// ---------------- prep: split fp32 -> (hi, lo) bf16 ----------------
__global__ void cvt_split(const float* __restrict__ in, __bf16* __restrict__ hi,
                          __bf16* __restrict__ lo, int n4) {
    int i = blockIdx.x * blockDim.x + threadIdx.x;
    if (i >= n4) return;
    f32x4 v = ((const f32x4*)in)[i];
    bf16x4 h, l;
#pragma unroll
    for (int j = 0; j < 4; ++j) {
        __bf16 hj = (__bf16)v[j];
        h[j] = hj;
        l[j] = (__bf16)(v[j] - (float)hj);
    }
    ((bf16x4*)hi)[i] = h;
    ((bf16x4*)lo)[i] = l;
}

// transpose + split weights into B^T layout: dst[rel*relstride + col*Ktot + koffbase + rel*koffstride + k]
__global__ void wprep(const float* __restrict__ W, __bf16* __restrict__ hi,
                      __bf16* __restrict__ lo, int K0, int NC, int Ktot,
                      int koffbase, int koffstride, int relstride) {
    int r = blockIdx.z;
    int idx = blockIdx.x * blockDim.x + threadIdx.x;
    if (idx >= K0 * NC) return;
    int k = idx / NC, c = idx % NC;
    float v = W[(size_t)r * K0 * NC + idx];
    __bf16 h = (__bf16)v;
    size_t o = (size_t)r * relstride + (size_t)c * Ktot + koffbase + r * koffstride + k;
    hi[o] = h;
    lo[o] = (__bf16)(v - (float)h);
}

// ---------------- per-(rel,dst) edge counts ----------------
__global__ void count_edges(const int* __restrict__ et, const int* __restrict__ dst,
                            int* __restrict__ cnt) {
    int e = blockIdx.x * blockDim.x + threadIdx.x;
    if (e < EE) atomicAdd(&cnt[et[e] * NN + dst[e]], 1);
}

// ---------------- exclusive scan of cnt[SEGS] -> cursor (3-pass) ----------------
__global__ void scan_partial(const int* __restrict__ cnt, int* __restrict__ bsum) {
    __shared__ int lds[SCAN_BS];
    const int b = blockIdx.x, t = threadIdx.x;
    const int base = b * SCAN_CHUNK + t * SCAN_ITEMS;
    int s = 0;
#pragma unroll
    for (int j = 0; j < SCAN_ITEMS; ++j) {
        int i = base + j;
        if (i < SEGS) s += cnt[i];
    }
    lds[t] = s;
    __syncthreads();
    for (int off = SCAN_BS / 2; off > 0; off >>= 1) {
        if (t < off) lds[t] += lds[t + off];
        __syncthreads();
    }
    if (t == 0) bsum[b] = lds[0];
}

__global__ void scan_bsum(int* __restrict__ bsum) {
    __shared__ int lds[512];
    const int t = threadIdx.x;
    const int v = (t < SCAN_NB) ? bsum[t] : 0;
    lds[t] = v;
    __syncthreads();
    for (int off = 1; off < 512; off <<= 1) {
        int x = (t >= off) ? lds[t - off] : 0;
        __syncthreads();
        lds[t] += x;
        __syncthreads();
    }
    if (t < SCAN_NB) bsum[t] = lds[t] - v;   // exclusive
}

__global__ void scan_final(const int* __restrict__ cnt, const int* __restrict__ bsum,
                           int* __restrict__ cursor) {
    __shared__ int lds[SCAN_BS];
    const int b = blockIdx.x, t = threadIdx.x;
    const int base = b * SCAN_CHUNK + t * SCAN_ITEMS;
    int v[SCAN_ITEMS];
    int s = 0;
#pragma unroll
    for (int j = 0; j < SCAN_ITEMS; ++j) {
        int i = base + j;
        v[j] = (i < SEGS) ? cnt[i] : 0;
        s += v[j];
    }
    lds[t] = s;
    __syncthreads();
    for (int off = 1; off < SCAN_BS; off <<= 1) {
        int x = (t >= off) ? lds[t - off] : 0;
        __syncthreads();
        lds[t] += x;
        __syncthreads();
    }
    int run = lds[t] - s + bsum[b];
#pragma unroll
    for (int j = 0; j < SCAN_ITEMS; ++j) {
        int i = base + j;
        if (i < SEGS) cursor[i] = run;
        run += v[j];
    }
}

// ---------------- bucket fill: esrc sorted by (rel,dst) segment ----------------
// after this pass, cursor[s] == segment END offset (begin = end - cnt[s])
__global__ void bucket_fill(const int* __restrict__ src, const int* __restrict__ dst,
                            const int* __restrict__ et, int* __restrict__ cursor,
                            int* __restrict__ esrc) {
    int e = blockIdx.x * blockDim.x + threadIdx.x;
    if (e < EE) {
        int s = et[e] * NN + dst[e];
        int pos = atomicAdd(&cursor[s], 1);
        esrc[pos] = src[e];
    }
}

// ---------------- split-bf16 MFMA GEMM, 128x128 tile, BK=32, dual A-source ----------------
// C[M,NC] = A[M,K] @ B^T[NC,K]^T  with A = [A1 (K<K1) | A2 (K>=K1)], all hi/lo split.
// 3-term split product. XCD-swizzled block map. LDS tiles use a 16B-chunk XOR swizzle
// (chunk' = chunk ^ ((row>>1)&3)) applied via pre-swizzled GLOBAL source (linear
// global_load_lds dest, rule #21) + swizzled ds_read offset -> 2-way (free) conflicts.
// EPI 0: C[o] = v            (xW)
// EPI 3: C[o] = v + bias[c]  (root-first h_pre / final out)
template <int K, int K1, int SA1, int SA2, int NC, int EPI>
__global__ __launch_bounds__(256, 4) void gemm_split(
    const __bf16* __restrict__ A1h, const __bf16* __restrict__ A1l,
    const __bf16* __restrict__ A2h, const __bf16* __restrict__ A2l,
    const __bf16* __restrict__ Bh, const __bf16* __restrict__ Bl,
    float* __restrict__ C, const float* __restrict__ bias, int M) {
    __shared__ __bf16 lds[16384];          // 32 KB: Ah|Al|Bh|Bl, each [128][32]
    __bf16* sAh = lds;
    __bf16* sAl = lds + 4096;
    __bf16* sBh = lds + 8192;
    __bf16* sBl = lds + 12288;

    constexpr int NT = NC / 128;           // 2 or 4 col-tiles

    // bijective XCD-aware swizzle (m204): same-XCD-consecutive blocks share an A panel
    const int nwg = gridDim.x;
    const int orig = blockIdx.x;
    const int q = nwg >> 3, r8 = nwg & 7;
    const int xcd = orig & 7, lin = orig >> 3;
    const int wg = (xcd < r8 ? xcd * (q + 1) : r8 * (q + 1) + (xcd - r8) * q) + lin;
    const int mtile = wg / NT, ntile = wg % NT;

    const int tid  = threadIdx.x;
    const int lane = tid & 63;
    const int wid  = tid >> 6;
    const int wm   = wid >> 1, wn = wid & 1;
    const int row0 = mtile * 128;
    const int col0 = ntile * 128;

    // staging source-chunk permutation (inverse of read swizzle); constant per thread
    const int kcs = (((tid & 3) ^ ((tid >> 3) & 3)) * 8);
    // fragment-read swizzled K-offset (replaces ko); constant per thread
    const int swz = (((lane >> 4) ^ ((lane >> 1) & 3)) * 8);

    f32x4 acc[4][4] = {};

    for (int ks = 0; ks < K / 32; ++ks) {
        const int k0 = ks * 32;
        const bool useA2 = (K1 < K) && (k0 >= K1);
#pragma unroll
        for (int i = 0; i < 2; ++i) {
            int flat = i * 256 + tid;          // 512 chunks of 8 bf16 per buffer
            int rr = flat >> 2;
            int ra = row0 + rr;
            ra = ra < M ? ra : M - 1;          // clamp tail rows (masked at store)
            const __bf16* gah = useA2 ? A2h + (size_t)ra * SA2 + (k0 - K1 + kcs)
                                      : A1h + (size_t)ra * SA1 + (k0 + kcs);
            const __bf16* gal = useA2 ? A2l + (size_t)ra * SA2 + (k0 - K1 + kcs)
                                      : A1l + (size_t)ra * SA1 + (k0 + kcs);
            size_t gb = (size_t)(col0 + rr) * K + k0 + kcs;
            gload_lds16(gah, sAh + flat * 8);
            gload_lds16(gal, sAl + flat * 8);
            gload_lds16(Bh + gb, sBh + flat * 8);
            gload_lds16(Bl + gb, sBl + flat * 8);
        }
        __syncthreads();
        {
            bf16x8 fah[4], fal[4], fbh[4], fbl[4];
#pragma unroll
            for (int m = 0; m < 4; ++m) {
                int ar = wm * 64 + m * 16 + (lane & 15);
                fah[m] = *(const bf16x8*)(sAh + ar * 32 + swz);
                fal[m] = *(const bf16x8*)(sAl + ar * 32 + swz);
            }
#pragma unroll
            for (int n = 0; n < 4; ++n) {
                int br = wn * 64 + n * 16 + (lane & 15);
                fbh[n] = *(const bf16x8*)(sBh + br * 32 + swz);
                fbl[n] = *(const bf16x8*)(sBl + br * 32 + swz);
            }
#pragma unroll
            for (int m = 0; m < 4; ++m)
#pragma unroll
                for (int n = 0; n < 4; ++n) {
                    acc[m][n] = mfma_bf16(fah[m], fbh[n], acc[m][n]);
                    acc[m][n] = mfma_bf16(fal[m], fbh[n], acc[m][n]);
                    acc[m][n] = mfma_bf16(fah[m], fbl[n], acc[m][n]);
                }
        }
        __syncthreads();
    }

#pragma unroll
    for (int m = 0; m < 4; ++m)
#pragma unroll
        for (int n = 0; n < 4; ++n)
#pragma unroll
            for (int q2 = 0; q2 < 4; ++q2) {
                int row = row0 + wm * 64 + m * 16 + (lane >> 4) * 4 + q2;
                int col = col0 + wn * 64 + n * 16 + (lane & 15);
                if (row < M) {
                    size_t o = (size_t)row * NC + col;
                    float v = acc[m][n][q2];
                    if (EPI == 3) v += bias[col];
                    C[o] = v;
                }
            }
}

// ---------------- L1 gather (2 relations per pass): h_pre[d] += sum of both rel-means ----------------
__global__ void gather_l1_pair(const float* __restrict__ xW0, const float* __restrict__ xW1,
                               const int* __restrict__ esrc, const int* __restrict__ cursor,
                               const int* __restrict__ cnt, float* __restrict__ h_pre,
                               int rel0) {
    const int d = blockIdx.x * 4 + (threadIdx.x >> 6);
    if (d >= NN) return;
    const int lane = threadIdx.x & 63;
    const int s0 = rel0 * NN + d;
    const int s1 = s0 + NN;
    const int n0 = cnt[s0], n1 = cnt[s1];
    if ((n0 | n1) == 0) return;
    f32x4 v = {};
    if (n0 > 0) {
        const int end = cursor[s0];
        f32x4 t = {};
        for (int i = end - n0; i < end; ++i)
            t += ((const f32x4*)(xW0 + (size_t)esrc[i] * CHID))[lane];
        v += t * (1.0f / (float)n0);
    }
    if (n1 > 0) {
        const int end = cursor[s1];
        f32x4 t = {};
        for (int i = end - n1; i < end; ++i)
            t += ((const f32x4*)(xW1 + (size_t)esrc[i] * CHID))[lane];
        v += t * (1.0f / (float)n1);
    }
    ((f32x4*)(h_pre + (size_t)d * CHID))[lane] += v;
}

// ---------------- finish1: h = relu(h_pre) -> split bf16 hi/lo ----------------
__global__ void finish1(const float* __restrict__ h_pre, __bf16* __restrict__ hh,
                        __bf16* __restrict__ hl) {
    int i = blockIdx.x * blockDim.x + threadIdx.x;
    if (i >= NN * CHID / 4) return;
    f32x4 v = ((const f32x4*)h_pre)[i];
    bf16x4 a, b;
#pragma unroll
    for (int j = 0; j < 4; ++j) {
        float x = fmaxf(v[j], 0.0f);
        __bf16 h = (__bf16)x;
        a[j] = h;
        b[j] = (__bf16)(x - (float)h);
    }
    ((bf16x4*)hh)[i] = a;
    ((bf16x4*)hl)[i] = b;
}

// ---------------- L2 gather-aggregate: G2[dloc, rel*256+c] = mean_{seg(rel,d)} h[src,c] ----------------
// one wave per (rel, dloc) segment; nontemporal stores keep h L3-resident
__global__ void gather_g2(const __bf16* __restrict__ hh, const __bf16* __restrict__ hl,
                          const int* __restrict__ esrc, const int* __restrict__ cursor,
                          const int* __restrict__ cnt, __bf16* __restrict__ G2h,
                          __bf16* __restrict__ G2l, int half) {
    const int sidx = blockIdx.x * 4 + (threadIdx.x >> 6);
    if (sidx >= RR * MHALF) return;
    const int lane = threadIdx.x & 63;
    const int rel = sidx / MHALF;
    const int dloc = sidx % MHALF;
    const int d = half * MHALF + dloc;
    const int s = rel * NN + d;
    const int n = cnt[s];
    f32x4 v = {};
    if (n > 0) {
        const int end = cursor[s];
        for (int i = end - n; i < end; ++i) {
            const size_t ro = (size_t)esrc[i] * CHID + lane * 4;
            bf16x4 a = *(const bf16x4*)(hh + ro);
            bf16x4 b = *(const bf16x4*)(hl + ro);
#pragma unroll
            for (int j = 0; j < 4; ++j) v[j] += (float)a[j] + (float)b[j];
        }
        const float inv = 1.0f / (float)n;
#pragma unroll
        for (int j = 0; j < 4; ++j) v[j] *= inv;
    }
    union { __bf16 b[4]; unsigned long long u; } ph, pl;
#pragma unroll
    for (int j = 0; j < 4; ++j) {
        __bf16 h = (__bf16)v[j];
        ph.b[j] = h;
        pl.b[j] = (__bf16)(v[j] - (float)h);
    }
    const size_t o = (size_t)dloc * K2S + rel * CHID + lane * 4;
    __builtin_nontemporal_store(ph.u, (unsigned long long*)(G2h + o));
    __builtin_nontemporal_store(pl.u, (unsigned long long*)(G2l + o));
}

// ---------------- row-wise L2 normalize (one wave per 512-col row) ----------------
__global__ void l2norm(float* __restrict__ out) {
    int row = blockIdx.x * 4 + (threadIdx.x >> 6);
    int lane = threadIdx.x & 63;
    if (row >= NN) return;
    float* p = out + (size_t)row * COUT;
    f32x4 a = ((const f32x4*)p)[lane];
    f32x4 b = ((const f32x4*)p)[lane + 64];
    float ss = a[0] * a[0] + a[1] * a[1] + a[2] * a[2] + a[3] * a[3] +
               b[0] * b[0] + b[1] * b[1] + b[2] * b[2] + b[3] * b[3];
#pragma unroll
    for (int m = 32; m >= 1; m >>= 1) ss += __shfl_xor(ss, m, 64);
    const float s = 1.0f / fmaxf(sqrtf(ss), 1e-12f);
#pragma unroll
    for (int j = 0; j < 4; ++j) { a[j] *= s; b[j] *= s; }
    ((f32x4*)p)[lane] = a;
    ((f32x4*)p)[lane + 64] = b;
}

extern "C" void kernel_launch(void* const* d_in, const int* in_sizes, int n_in,
                              void* d_out, int out_size, void* d_ws, size_t ws_size,
                              hipStream_t stream) {
    (void)in_sizes; (void)n_in; (void)out_size; (void)ws_size;
    const float* x  = (const float*)d_in[0];
    const float* W1 = (const float*)d_in[1];
    const float* r1 = (const float*)d_in[2];
    const float* b1 = (const float*)d_in[3];
    const float* W2 = (const float*)d_in[4];
    const float* r2 = (const float*)d_in[5];
    const float* b2 = (const float*)d_in[6];
    const int* src = (const int*)d_in[7];
    const int* dst = (const int*)d_in[8];
    const int* et  = (const int*)d_in[9];
    float* out = (float*)d_out;

    char* w = (char*)d_ws;
    auto take = [&](size_t bytes) {
        char* p = w;
        w += (bytes + 255) & ~(size_t)255;
        return p;
    };
    int*    cnt    = (int*)   take((size_t)SEGS * 4);
    int*    cursor = (int*)   take((size_t)SEGS * 4);
    int*    bsum   = (int*)   take((size_t)SCAN_NB * 4);
    int*    esrc   = (int*)   take((size_t)EE * 4);
    __bf16* x_hi  = (__bf16*)take((size_t)NN * CIN * 2);
    __bf16* x_lo  = (__bf16*)take((size_t)NN * CIN * 2);
    __bf16* hh    = (__bf16*)take((size_t)NN * CHID * 2);
    __bf16* hl    = (__bf16*)take((size_t)NN * CHID * 2);
    __bf16* W1t_h = (__bf16*)take((size_t)RR * CIN * CHID * 2);
    __bf16* W1t_l = (__bf16*)take((size_t)RR * CIN * CHID * 2);
    __bf16* r1t_h = (__bf16*)take((size_t)CIN * CHID * 2);
    __bf16* r1t_l = (__bf16*)take((size_t)CIN * CHID * 2);
    __bf16* W2c_h = (__bf16*)take((size_t)COUT * K2 * 2);   // [512 cols][2304] catted rels+root
    __bf16* W2c_l = (__bf16*)take((size_t)COUT * K2 * 2);
    // arena reused across phases.
    // L1 phase: xW0 (51.2 MB) + xW1 (51.2 MB) + h_pre (51.2 MB).
    // L2 phase: G2 hi/lo (204.8 MB) — valid since h_pre is dead after finish1.
    char* arena = take((size_t)MHALF * K2S * 2 * 2);
    float*  xW0   = (float*)arena;
    float*  xW1   = (float*)(arena + (size_t)NN * CHID * 4);
    float*  h_pre = (float*)(arena + (size_t)NN * CHID * 8);
    __bf16* G2h   = (__bf16*)arena;                              // [25000][2048]
    __bf16* G2l   = (__bf16*)(arena + (size_t)MHALF * K2S * 2);

    hipMemsetAsync(cnt, 0, (size_t)SEGS * 4, stream);

    cvt_split<<<(NN * CIN / 4 + 255) / 256, 256, 0, stream>>>(x, x_hi, x_lo, NN * CIN / 4);
    // W1[r][512][256] -> W1t[r][256][512]
    wprep<<<dim3((CIN * CHID + 255) / 256, 1, RR), 256, 0, stream>>>(
        W1, W1t_h, W1t_l, CIN, CHID, CIN, 0, 0, CIN * CHID);
    wprep<<<dim3((CIN * CHID + 255) / 256, 1, 1), 256, 0, stream>>>(
        r1, r1t_h, r1t_l, CIN, CHID, CIN, 0, 0, 0);
    // W2[r][256][512] -> W2cat[512][r*256 + k];  root2 -> W2cat[512][2048 + k]
    wprep<<<dim3((CHID * COUT + 255) / 256, 1, RR), 256, 0, stream>>>(
        W2, W2c_h, W2c_l, CHID, COUT, K2, 0, CHID, 0);
    wprep<<<dim3((CHID * COUT + 255) / 256, 1, 1), 256, 0, stream>>>(
        r2, W2c_h, W2c_l, CHID, COUT, K2, K2S, 0, 0);

    // counting sort of edges by (rel,dst)
    count_edges<<<(EE + 255) / 256, 256, 0, stream>>>(et, dst, cnt);
    scan_partial<<<SCAN_NB, SCAN_BS, 0, stream>>>(cnt, bsum);
    scan_bsum<<<1, 512, 0, stream>>>(bsum);
    scan_final<<<SCAN_NB, SCAN_BS, 0, stream>>>(cnt, bsum, cursor);
    bucket_fill<<<(EE + 255) / 256, 256, 0, stream>>>(src, dst, et, cursor, esrc);

    const int MT1 = (NN + 127) / 128;     // 391
    const int MT2 = (MHALF + 127) / 128;  // 196

    // ---- layer 1: root-first, then per-relation-pair transform + gather-RMW ----
    gemm_split<CIN, CIN, CIN, CIN, CHID, 3><<<MT1 * 2, 256, 0, stream>>>(
        x_hi, x_lo, x_hi, x_lo, r1t_h, r1t_l, h_pre, b1, NN);
    for (int rp = 0; rp < RR / 2; ++rp) {
        const int rel = rp * 2;
        gemm_split<CIN, CIN, CIN, CIN, CHID, 0><<<MT1 * 2, 256, 0, stream>>>(
            x_hi, x_lo, x_hi, x_lo,
            W1t_h + (size_t)rel * CIN * CHID, W1t_l + (size_t)rel * CIN * CHID,
            xW0, nullptr, NN);
        gemm_split<CIN, CIN, CIN, CIN, CHID, 0><<<MT1 * 2, 256, 0, stream>>>(
            x_hi, x_lo, x_hi, x_lo,
            W1t_h + (size_t)(rel + 1) * CIN * CHID, W1t_l + (size_t)(rel + 1) * CIN * CHID,
            xW1, nullptr, NN);
        gather_l1_pair<<<(NN + 3) / 4, 256, 0, stream>>>(xW0, xW1, esrc, cursor, cnt,
                                                         h_pre, rel);
    }
    finish1<<<(NN * CHID / 4 + 255) / 256, 256, 0, stream>>>(h_pre, hh, hl);

    // ---- layer 2: aggregate-then-transform, two M-halves, single K=2304 GEMM each ----
    for (int half = 0; half < 2; ++half) {
        gather_g2<<<(RR * MHALF + 3) / 4, 256, 0, stream>>>(hh, hl, esrc, cursor, cnt,
                                                            G2h, G2l, half);
        gemm_split<K2, K2S, K2S, CHID, COUT, 3><<<MT2 * 4, 256, 0, stream>>>(
            G2h, G2l, hh + (size_t)half * MHALF * CHID, hl + (size_t)half * MHALF * CHID,
            W2c_h, W2c_l, out + (size_t)half * MHALF * COUT, b2, MHALF);
    }

    l2norm<<<(NN + 3) / 4, 256, 0, stream>>>(out);
}